// Round 1
// baseline (105.483 us; speedup 1.0000x reference)
//
#include <hip/hip_runtime.h>

#define N_ROWS 32768
#define N_COLS 1000
#define NBINS  10

// bin(g) with g = sigmoid(v) (non-target) mapped into x-space:
// bin = #{k in 1..9 : v >= logit(k/10)}
__device__ __forceinline__ int bin_of(float v) {
    int b = 0;
    b += (v >= -2.19722458f);  // logit(0.1)
    b += (v >= -1.38629436f);  // logit(0.2)
    b += (v >= -0.84729786f);  // logit(0.3)
    b += (v >= -0.40546511f);  // logit(0.4)
    b += (v >=  0.0f);         // logit(0.5)
    b += (v >=  0.40546511f);  // logit(0.6)
    b += (v >=  0.84729786f);  // logit(0.7)
    b += (v >=  1.38629436f);  // logit(0.8)
    b += (v >=  2.19722458f);  // logit(0.9)
    return b;
}

extern "C" __global__ __launch_bounds__(256)
void ghm_hist(const float* __restrict__ x, const int* __restrict__ target,
              unsigned int* __restrict__ counts) {
    // per-thread private histogram in LDS, stride 11 (gcd(11,32)=1 -> conflict-free)
    __shared__ unsigned int h[256][11];
    const int tid = threadIdx.x;
#pragma unroll
    for (int b = 0; b < 11; ++b) h[tid][b] = 0;

    for (int row = blockIdx.x; row < N_ROWS; row += gridDim.x) {
        const int t = target[row];
        if (tid < 250) {
            const float4 v = reinterpret_cast<const float4*>(x + (size_t)row * N_COLS)[tid];
            const int j0 = tid * 4;
            // target element uses g = 1 - sigmoid(x) = sigmoid(-x)
            const float a0 = (j0 + 0 == t) ? -v.x : v.x;
            const float a1 = (j0 + 1 == t) ? -v.y : v.y;
            const float a2 = (j0 + 2 == t) ? -v.z : v.z;
            const float a3 = (j0 + 3 == t) ? -v.w : v.w;
            h[tid][bin_of(a0)]++;
            h[tid][bin_of(a1)]++;
            h[tid][bin_of(a2)]++;
            h[tid][bin_of(a3)]++;
        }
    }
    __syncthreads();
    // fold 256 thread-histograms: 4->1 in LDS, then wave-0 butterfly per bin
    if (tid < 64) {
        unsigned int mysum = 0;
#pragma unroll
        for (int b = 0; b < NBINS; ++b) {
            unsigned int s = h[tid][b] + h[tid + 64][b] + h[tid + 128][b] + h[tid + 192][b];
#pragma unroll
            for (int off = 32; off >= 1; off >>= 1)
                s += (unsigned int)__shfl_xor((int)s, off);
            if (tid == b) mysum = s;   // lane b keeps bin b's total
        }
        if (tid < NBINS) atomicAdd(&counts[tid], mysum);
    }
}

extern "C" __global__ __launch_bounds__(256)
void ghm_row(const float* __restrict__ x, const int* __restrict__ target,
             const unsigned int* __restrict__ counts, float* __restrict__ rowloss) {
    __shared__ float logcnt[NBINS];
    __shared__ float redbuf[4];
    __shared__ float s_xt;
    __shared__ int   s_bt;
    const int row = blockIdx.x;
    const int tid = threadIdx.x;
    const int t   = target[row];
    const float* xrow = x + (size_t)row * N_COLS;

    if (tid < NBINS) {
        unsigned int c = counts[tid];
        logcnt[tid] = __logf((float)(c < 1u ? 1u : c));
    }
    if (tid == 0) {
        const float xt = xrow[t];
        s_xt = xt;
        s_bt = bin_of(-xt);     // target element: g = sigmoid(-x)
    }
    __syncthreads();
    const float xt  = s_xt;
    const float lwt = logcnt[s_bt];

    float w0 = -INFINITY, w1 = -INFINITY, w2 = -INFINITY, w3 = -INFINITY;
    if (tid < 250) {
        const float4 v = reinterpret_cast<const float4*>(xrow)[tid];
        const int j0 = tid * 4;
        // wx = x + min(log cnt[bin] - log cnt[bin_t], 0); at j==t weight==1 -> wx = x
        w0 = (j0 + 0 == t) ? v.x : v.x + fminf(logcnt[bin_of(v.x)] - lwt, 0.0f);
        w1 = (j0 + 1 == t) ? v.y : v.y + fminf(logcnt[bin_of(v.y)] - lwt, 0.0f);
        w2 = (j0 + 2 == t) ? v.z : v.z + fminf(logcnt[bin_of(v.z)] - lwt, 0.0f);
        w3 = (j0 + 3 == t) ? v.w : v.w + fminf(logcnt[bin_of(v.w)] - lwt, 0.0f);
    }

    // row max
    float m = fmaxf(fmaxf(w0, w1), fmaxf(w2, w3));
#pragma unroll
    for (int off = 32; off >= 1; off >>= 1) m = fmaxf(m, __shfl_xor(m, off));
    const int wid = tid >> 6, lane = tid & 63;
    if (lane == 0) redbuf[wid] = m;
    __syncthreads();
    m = fmaxf(fmaxf(redbuf[0], redbuf[1]), fmaxf(redbuf[2], redbuf[3]));

    // sum of exp
    float s = 0.0f;
    if (tid < 250) {
        s = __expf(w0 - m) + __expf(w1 - m) + __expf(w2 - m) + __expf(w3 - m);
    }
#pragma unroll
    for (int off = 32; off >= 1; off >>= 1) s += __shfl_xor(s, off);
    __syncthreads();                    // redbuf reuse guard
    if (lane == 0) redbuf[wid] = s;
    __syncthreads();
    if (tid == 0) {
        const float tot = redbuf[0] + redbuf[1] + redbuf[2] + redbuf[3];
        rowloss[row] = m + __logf(tot) - xt;   // lse - x_target
    }
}

extern "C" __global__ __launch_bounds__(256)
void ghm_reduce(const float* __restrict__ rowloss, float* __restrict__ out) {
    __shared__ float redbuf[4];
    const int tid = threadIdx.x;
    float s = 0.0f;
    const float4* rl4 = reinterpret_cast<const float4*>(rowloss);
#pragma unroll 4
    for (int i = tid; i < N_ROWS / 4; i += 256) {
        const float4 v = rl4[i];
        s += (v.x + v.y) + (v.z + v.w);
    }
#pragma unroll
    for (int off = 32; off >= 1; off >>= 1) s += __shfl_xor(s, off);
    const int wid = tid >> 6, lane = tid & 63;
    if (lane == 0) redbuf[wid] = s;
    __syncthreads();
    if (tid == 0)
        out[0] = (redbuf[0] + redbuf[1] + redbuf[2] + redbuf[3]) / (float)N_ROWS;
}

extern "C" void kernel_launch(void* const* d_in, const int* in_sizes, int n_in,
                              void* d_out, int out_size, void* d_ws, size_t ws_size,
                              hipStream_t stream) {
    const float* x      = (const float*)d_in[0];
    const int*   target = (const int*)d_in[1];
    unsigned int* counts  = (unsigned int*)d_ws;
    float*        rowloss = (float*)((char*)d_ws + 64);

    hipMemsetAsync(d_ws, 0, 64, stream);
    hipLaunchKernelGGL(ghm_hist,   dim3(2048),   dim3(256), 0, stream, x, target, counts);
    hipLaunchKernelGGL(ghm_row,    dim3(N_ROWS), dim3(256), 0, stream, x, target, counts, rowloss);
    hipLaunchKernelGGL(ghm_reduce, dim3(1),      dim3(256), 0, stream, rowloss, (float*)d_out);
}

// Round 2
// 102.634 us; speedup vs baseline: 1.0278x; 1.0278x over previous
//
#include <hip/hip_runtime.h>

#define N_ROWS     32768
#define N_COLS     1000
#define NBINS      10
#define HIST_BLKS  2048

// bin(g) with g = sigmoid(v) (non-target) mapped into x-space:
// bin = #{k in 1..9 : v >= logit(k/10)}
__device__ __forceinline__ int bin_of(float v) {
    int b = 0;
    b += (v >= -2.19722458f);  // logit(0.1)
    b += (v >= -1.38629436f);  // logit(0.2)
    b += (v >= -0.84729786f);  // logit(0.3)
    b += (v >= -0.40546511f);  // logit(0.4)
    b += (v >=  0.0f);         // logit(0.5)
    b += (v >=  0.40546511f);  // logit(0.6)
    b += (v >=  0.84729786f);  // logit(0.7)
    b += (v >=  1.38629436f);  // logit(0.8)
    b += (v >=  2.19722458f);  // logit(0.9)
    return b;
}

// Stage 1: per-block partial histograms, NO atomics, NO zero-init needed
// (each block fully overwrites its own 10-entry slot).
extern "C" __global__ __launch_bounds__(256)
void ghm_hist(const float* __restrict__ x, const int* __restrict__ target,
              unsigned int* __restrict__ partial) {
    // per-thread private histogram in LDS, stride 11 (gcd(11,32)=1 -> conflict-free)
    __shared__ unsigned int h[256][11];
    const int tid = threadIdx.x;
#pragma unroll
    for (int b = 0; b < 11; ++b) h[tid][b] = 0;

    for (int row = blockIdx.x; row < N_ROWS; row += gridDim.x) {
        const int t = target[row];
        if (tid < 250) {
            const float4 v = reinterpret_cast<const float4*>(x + (size_t)row * N_COLS)[tid];
            const int j0 = tid * 4;
            // target element uses g = 1 - sigmoid(x) = sigmoid(-x)
            const float a0 = (j0 + 0 == t) ? -v.x : v.x;
            const float a1 = (j0 + 1 == t) ? -v.y : v.y;
            const float a2 = (j0 + 2 == t) ? -v.z : v.z;
            const float a3 = (j0 + 3 == t) ? -v.w : v.w;
            h[tid][bin_of(a0)]++;
            h[tid][bin_of(a1)]++;
            h[tid][bin_of(a2)]++;
            h[tid][bin_of(a3)]++;
        }
    }
    __syncthreads();
    // fold 256 thread-histograms: 4->1, then wave-0 butterfly per bin
    if (tid < 64) {
        unsigned int mysum = 0;
#pragma unroll
        for (int b = 0; b < NBINS; ++b) {
            unsigned int s = h[tid][b] + h[tid + 64][b] + h[tid + 128][b] + h[tid + 192][b];
#pragma unroll
            for (int off = 32; off >= 1; off >>= 1)
                s += (unsigned int)__shfl_xor((int)s, off);
            if (tid == b) mysum = s;   // lane b keeps bin b's total
        }
        if (tid < NBINS) partial[blockIdx.x * NBINS + tid] = mysum;
    }
}

// Stage 1b: reduce HIST_BLKS partial histograms -> counts. One wave per bin.
extern "C" __global__ __launch_bounds__(640)
void ghm_sum(const unsigned int* __restrict__ partial, unsigned int* __restrict__ counts) {
    const int b    = threadIdx.x >> 6;   // bin 0..9
    const int lane = threadIdx.x & 63;
    unsigned int s = 0;
    for (int k = lane; k < HIST_BLKS; k += 64) s += partial[k * NBINS + b];
#pragma unroll
    for (int off = 32; off >= 1; off >>= 1) s += (unsigned int)__shfl_xor((int)s, off);
    if (lane == 0) counts[b] = s;
}

// Stage 2: per-row weighted log-softmax loss contribution.
extern "C" __global__ __launch_bounds__(256)
void ghm_row(const float* __restrict__ x, const int* __restrict__ target,
             const unsigned int* __restrict__ counts, float* __restrict__ rowloss) {
    __shared__ float logcnt[NBINS];
    __shared__ float redbuf[4];
    __shared__ float s_xt;
    __shared__ int   s_bt;
    const int row = blockIdx.x;
    const int tid = threadIdx.x;
    const int t   = target[row];
    const float* xrow = x + (size_t)row * N_COLS;

    if (tid < NBINS) {
        unsigned int c = counts[tid];
        logcnt[tid] = __logf((float)(c < 1u ? 1u : c));
    }
    if (tid == 0) {
        const float xt = xrow[t];
        s_xt = xt;
        s_bt = bin_of(-xt);     // target element: g = sigmoid(-x)
    }
    __syncthreads();
    const float xt  = s_xt;
    const float lwt = logcnt[s_bt];

    float w0 = -INFINITY, w1 = -INFINITY, w2 = -INFINITY, w3 = -INFINITY;
    if (tid < 250) {
        const float4 v = reinterpret_cast<const float4*>(xrow)[tid];
        const int j0 = tid * 4;
        // wx = x + min(log cnt[bin] - log cnt[bin_t], 0); at j==t weight==1 -> wx = x
        w0 = (j0 + 0 == t) ? v.x : v.x + fminf(logcnt[bin_of(v.x)] - lwt, 0.0f);
        w1 = (j0 + 1 == t) ? v.y : v.y + fminf(logcnt[bin_of(v.y)] - lwt, 0.0f);
        w2 = (j0 + 2 == t) ? v.z : v.z + fminf(logcnt[bin_of(v.z)] - lwt, 0.0f);
        w3 = (j0 + 3 == t) ? v.w : v.w + fminf(logcnt[bin_of(v.w)] - lwt, 0.0f);
    }

    // row max
    float m = fmaxf(fmaxf(w0, w1), fmaxf(w2, w3));
#pragma unroll
    for (int off = 32; off >= 1; off >>= 1) m = fmaxf(m, __shfl_xor(m, off));
    const int wid = tid >> 6, lane = tid & 63;
    if (lane == 0) redbuf[wid] = m;
    __syncthreads();
    m = fmaxf(fmaxf(redbuf[0], redbuf[1]), fmaxf(redbuf[2], redbuf[3]));

    // sum of exp
    float s = 0.0f;
    if (tid < 250) {
        s = __expf(w0 - m) + __expf(w1 - m) + __expf(w2 - m) + __expf(w3 - m);
    }
#pragma unroll
    for (int off = 32; off >= 1; off >>= 1) s += __shfl_xor(s, off);
    __syncthreads();                    // redbuf reuse guard
    if (lane == 0) redbuf[wid] = s;
    __syncthreads();
    if (tid == 0) {
        const float tot = redbuf[0] + redbuf[1] + redbuf[2] + redbuf[3];
        rowloss[row] = m + __logf(tot) - xt;   // lse - x_target
    }
}

// Stage 3: mean over rows.
extern "C" __global__ __launch_bounds__(256)
void ghm_reduce(const float* __restrict__ rowloss, float* __restrict__ out) {
    __shared__ float redbuf[4];
    const int tid = threadIdx.x;
    float s = 0.0f;
    const float4* rl4 = reinterpret_cast<const float4*>(rowloss);
#pragma unroll 4
    for (int i = tid; i < N_ROWS / 4; i += 256) {
        const float4 v = rl4[i];
        s += (v.x + v.y) + (v.z + v.w);
    }
#pragma unroll
    for (int off = 32; off >= 1; off >>= 1) s += __shfl_xor(s, off);
    const int wid = tid >> 6, lane = tid & 63;
    if (lane == 0) redbuf[wid] = s;
    __syncthreads();
    if (tid == 0)
        out[0] = (redbuf[0] + redbuf[1] + redbuf[2] + redbuf[3]) / (float)N_ROWS;
}

extern "C" void kernel_launch(void* const* d_in, const int* in_sizes, int n_in,
                              void* d_out, int out_size, void* d_ws, size_t ws_size,
                              hipStream_t stream) {
    const float* x      = (const float*)d_in[0];
    const int*   target = (const int*)d_in[1];
    // ws layout: [partial: HIST_BLKS*NBINS u32][counts: NBINS u32 (aligned 64)][rowloss: N_ROWS f32]
    unsigned int* partial = (unsigned int*)d_ws;
    unsigned int* counts  = (unsigned int*)((char*)d_ws + HIST_BLKS * NBINS * sizeof(unsigned int));
    float*        rowloss = (float*)((char*)d_ws + HIST_BLKS * NBINS * sizeof(unsigned int) + 64);

    hipLaunchKernelGGL(ghm_hist,   dim3(HIST_BLKS), dim3(256), 0, stream, x, target, partial);
    hipLaunchKernelGGL(ghm_sum,    dim3(1),         dim3(640), 0, stream, partial, counts);
    hipLaunchKernelGGL(ghm_row,    dim3(N_ROWS),    dim3(256), 0, stream, x, target, counts, rowloss);
    hipLaunchKernelGGL(ghm_reduce, dim3(1),         dim3(256), 0, stream, rowloss, (float*)d_out);
}

// Round 3
// 91.266 us; speedup vs baseline: 1.1558x; 1.1246x over previous
//
#include <hip/hip_runtime.h>

#define N_ROWS     32768
#define N_COLS     1000
#define NBINS      10
#define HIST_BLKS  2048

// bin(g) with g = sigmoid(v) mapped into x-space: bin = #{k in 1..9 : v >= logit(k/10)}
__device__ __forceinline__ int bin_of(float v) {
    int b = 0;
    b += (v >= -2.19722458f);  // logit(0.1)
    b += (v >= -1.38629436f);  // logit(0.2)
    b += (v >= -0.84729786f);  // logit(0.3)
    b += (v >= -0.40546511f);  // logit(0.4)
    b += (v >=  0.0f);         // logit(0.5)
    b += (v >=  0.40546511f);  // logit(0.6)
    b += (v >=  0.84729786f);  // logit(0.7)
    b += (v >=  1.38629436f);  // logit(0.8)
    b += (v >=  2.19722458f);  // logit(0.9)
    return b;
}

// Stage 1: per-block partial histograms, no atomics, no zero-init needed.
extern "C" __global__ __launch_bounds__(256)
void ghm_hist(const float* __restrict__ x, const int* __restrict__ target,
              unsigned int* __restrict__ partial) {
    __shared__ unsigned int h[256][11];   // stride 11: conflict-free per-thread hist
    const int tid = threadIdx.x;
#pragma unroll
    for (int b = 0; b < 11; ++b) h[tid][b] = 0;

    for (int row = blockIdx.x; row < N_ROWS; row += HIST_BLKS) {
        const int t = target[row];
        if (tid < 250) {
            const float4 v = reinterpret_cast<const float4*>(x + (size_t)row * N_COLS)[tid];
            const int j0 = tid * 4;
            const float a0 = (j0 + 0 == t) ? -v.x : v.x;   // target: g = sigmoid(-x)
            const float a1 = (j0 + 1 == t) ? -v.y : v.y;
            const float a2 = (j0 + 2 == t) ? -v.z : v.z;
            const float a3 = (j0 + 3 == t) ? -v.w : v.w;
            h[tid][bin_of(a0)]++;
            h[tid][bin_of(a1)]++;
            h[tid][bin_of(a2)]++;
            h[tid][bin_of(a3)]++;
        }
    }
    __syncthreads();
    if (tid < 64) {
        unsigned int mysum = 0;
#pragma unroll
        for (int b = 0; b < NBINS; ++b) {
            unsigned int s = h[tid][b] + h[tid + 64][b] + h[tid + 128][b] + h[tid + 192][b];
#pragma unroll
            for (int off = 32; off >= 1; off >>= 1)
                s += (unsigned int)__shfl_xor((int)s, off);
            if (tid == b) mysum = s;
        }
        if (tid < NBINS) partial[blockIdx.x * NBINS + tid] = mysum;
    }
}

// Stage 1b: reduce HIST_BLKS partial histograms -> counts. One wave per bin.
extern "C" __global__ __launch_bounds__(640)
void ghm_sum(const unsigned int* __restrict__ partial, unsigned int* __restrict__ counts) {
    const int b    = threadIdx.x >> 6;
    const int lane = threadIdx.x & 63;
    unsigned int s = 0;
    for (int k = lane; k < HIST_BLKS; k += 64) s += partial[k * NBINS + b];
#pragma unroll
    for (int off = 32; off >= 1; off >>= 1) s += (unsigned int)__shfl_xor((int)s, off);
    if (lane == 0) counts[b] = s;
}

// Stage 2: one WAVE per row. loss_row = log( sum_j w_j e^{x_j} ) - x_t,
// w_j = min(cnt[bin_j]/cnt[bin_t],1) (=1 at j==t). No block syncs in the row loop.
// Each block accumulates its 16 rows' losses into one partial.
extern "C" __global__ __launch_bounds__(256)
void ghm_row2(const float* __restrict__ x, const int* __restrict__ target,
              const unsigned int* __restrict__ counts, float* __restrict__ blockloss) {
    __shared__ float wtab[4][NBINS];   // per-wave weight table
    __shared__ float wloss[4];
    const int tid = threadIdx.x, wid = tid >> 6, lane = tid & 63;
    float lsum = 0.0f;

    for (int row = blockIdx.x * 4 + wid; row < N_ROWS; row += HIST_BLKS * 4) {
        const int t = target[row];
        const float* xrow = x + (size_t)row * N_COLS;
        const float xt = xrow[t];                 // wave-uniform address -> broadcast
        const int bt = bin_of(-xt);               // target bin uses g = sigmoid(-x)
        const float inv_ct = 1.0f / (float)counts[bt];
        if (lane < NBINS)
            wtab[wid][lane] = fminf((float)counts[lane] * inv_ct, 1.0f);
        // same-wave ds_write -> ds_read on same array: compiler inserts lgkmcnt

        float acc = 0.0f;
#pragma unroll
        for (int k = 0; k < 4; ++k) {
            const int f4 = k * 64 + lane;         // 250 float4 per row
            if (f4 < 250) {
                const float4 v = reinterpret_cast<const float4*>(xrow)[f4];
                const int j0 = f4 * 4;
                const float w0 = (j0 + 0 == t) ? 1.0f : wtab[wid][bin_of(v.x)];
                const float w1 = (j0 + 1 == t) ? 1.0f : wtab[wid][bin_of(v.y)];
                const float w2 = (j0 + 2 == t) ? 1.0f : wtab[wid][bin_of(v.z)];
                const float w3 = (j0 + 3 == t) ? 1.0f : wtab[wid][bin_of(v.w)];
                acc += w0 * __expf(v.x) + w1 * __expf(v.y)
                     + w2 * __expf(v.z) + w3 * __expf(v.w);
            }
        }
#pragma unroll
        for (int off = 32; off >= 1; off >>= 1) acc += __shfl_xor(acc, off);
        lsum += __logf(acc) - xt;                 // identical on all lanes
    }

    if (lane == 0) wloss[wid] = lsum;
    __syncthreads();
    if (tid == 0)
        blockloss[blockIdx.x] = (wloss[0] + wloss[1]) + (wloss[2] + wloss[3]);
}

// Stage 3: mean over block partials.
extern "C" __global__ __launch_bounds__(256)
void ghm_reduce2(const float* __restrict__ blockloss, float* __restrict__ out) {
    __shared__ float redbuf[4];
    const int tid = threadIdx.x;
    float s = 0.0f;
#pragma unroll
    for (int i = tid; i < HIST_BLKS; i += 256) s += blockloss[i];
#pragma unroll
    for (int off = 32; off >= 1; off >>= 1) s += __shfl_xor(s, off);
    const int wid = tid >> 6, lane = tid & 63;
    if (lane == 0) redbuf[wid] = s;
    __syncthreads();
    if (tid == 0)
        out[0] = ((redbuf[0] + redbuf[1]) + (redbuf[2] + redbuf[3])) / (float)N_ROWS;
}

extern "C" void kernel_launch(void* const* d_in, const int* in_sizes, int n_in,
                              void* d_out, int out_size, void* d_ws, size_t ws_size,
                              hipStream_t stream) {
    const float* x      = (const float*)d_in[0];
    const int*   target = (const int*)d_in[1];
    // ws layout: [partial: 2048*10 u32 = 80KB][counts: 10 u32][pad][blockloss: 2048 f32]
    unsigned int* partial   = (unsigned int*)d_ws;
    unsigned int* counts    = (unsigned int*)((char*)d_ws + HIST_BLKS * NBINS * sizeof(unsigned int));
    float*        blockloss = (float*)((char*)d_ws + HIST_BLKS * NBINS * sizeof(unsigned int) + 64);

    hipLaunchKernelGGL(ghm_hist,    dim3(HIST_BLKS), dim3(256), 0, stream, x, target, partial);
    hipLaunchKernelGGL(ghm_sum,     dim3(1),         dim3(640), 0, stream, partial, counts);
    hipLaunchKernelGGL(ghm_row2,    dim3(HIST_BLKS), dim3(256), 0, stream, x, target, counts, blockloss);
    hipLaunchKernelGGL(ghm_reduce2, dim3(1),         dim3(256), 0, stream, blockloss, (float*)d_out);
}

// Round 5
// 59.235 us; speedup vs baseline: 1.7807x; 1.5407x over previous
//
#include <hip/hip_runtime.h>

#define N_ROWS   32768
#define N_COLS   1000
#define NBINS    10
#define K1_BLKS  2048
#define K2_BLKS  128
#define C0_TOTAL 32768000.0f   // = 125 * 2^18, exact in f32

// bin(v) = #{k in 1..9 : v >= logit(k/10)}
__device__ __forceinline__ int bin_of(float v) {
    int b = 0;
    b += (v >= -2.19722458f);
    b += (v >= -1.38629436f);
    b += (v >= -0.84729786f);
    b += (v >= -0.40546511f);
    b += (v >=  0.0f);
    b += (v >=  0.40546511f);
    b += (v >=  0.84729786f);
    b += (v >=  1.38629436f);
    b += (v >=  2.19722458f);
    return b;
}

#define BFLY_F(v) do { v += __shfl_xor(v, 32); v += __shfl_xor(v, 16); \
                       v += __shfl_xor(v, 8);  v += __shfl_xor(v, 4);  \
                       v += __shfl_xor(v, 2);  v += __shfl_xor(v, 1); } while (0)
#define BFLY_U(v) do { v += (unsigned)__shfl_xor((int)(v), 32); \
                       v += (unsigned)__shfl_xor((int)(v), 16); \
                       v += (unsigned)__shfl_xor((int)(v), 8);  \
                       v += (unsigned)__shfl_xor((int)(v), 4);  \
                       v += (unsigned)__shfl_xor((int)(v), 2);  \
                       v += (unsigned)__shfl_xor((int)(v), 1); } while (0)

// K1: one wave per row (4 rows/wave). Per row: cumulative exp-sums
// T_k = sum_{x >= E_k} e^x (T_0 = full sum), written as 12 floats/row.
// Per thread: cumulative g-histogram counts C_k = #{g-val >= E_k}
// (natural x for all elems; lane 0 corrects the one target elem per row).
// Also zeroes K2's ticket.
extern "C" __global__ __launch_bounds__(256)
void ghm_pass1(const float* __restrict__ x, const int* __restrict__ target,
               unsigned int* __restrict__ partialC, float* __restrict__ Trows,
               unsigned int* __restrict__ ticket) {
    __shared__ unsigned int cw[4][9];
    const int tid = threadIdx.x, wid = tid >> 6, lane = tid & 63;
    const int bid = blockIdx.x;
    if (bid == 0 && tid == 0) *ticket = 0u;

    const float E1 = -2.19722458f, E2 = -1.38629436f, E3 = -0.84729786f,
                E4 = -0.40546511f, E5 = 0.0f,         E6 = 0.40546511f,
                E7 = 0.84729786f,  E8 = 1.38629436f,  E9 = 2.19722458f;

    unsigned int C1=0,C2=0,C3=0,C4=0,C5=0,C6=0,C7=0,C8=0,C9=0;

#pragma unroll 1
    for (int r = 0; r < 4; ++r) {
        const int row = bid * 4 + wid + r * (K1_BLKS * 4);
        const int t = target[row];
        const float* xrow = x + (size_t)row * N_COLS;
        const float xt = xrow[t];          // wave-uniform -> broadcast; overlaps k-loop
        float T0=0,T1=0,T2=0,T3=0,T4=0,T5=0,T6=0,T7=0,T8=0,T9=0;
#pragma unroll
        for (int k = 0; k < 4; ++k) {
            const int f4 = k * 64 + lane;                 // 250 float4 per row
            if (f4 < 250) {
                const float4 v = reinterpret_cast<const float4*>(xrow)[f4];
#define ACC(c) do { const float e_ = __expf(c); T0 += e_; \
                T1 += ((c) >= E1) ? e_ : 0.f;  C1 += ((c) >= E1); \
                T2 += ((c) >= E2) ? e_ : 0.f;  C2 += ((c) >= E2); \
                T3 += ((c) >= E3) ? e_ : 0.f;  C3 += ((c) >= E3); \
                T4 += ((c) >= E4) ? e_ : 0.f;  C4 += ((c) >= E4); \
                T5 += ((c) >= E5) ? e_ : 0.f;  C5 += ((c) >= E5); \
                T6 += ((c) >= E6) ? e_ : 0.f;  C6 += ((c) >= E6); \
                T7 += ((c) >= E7) ? e_ : 0.f;  C7 += ((c) >= E7); \
                T8 += ((c) >= E8) ? e_ : 0.f;  C8 += ((c) >= E8); \
                T9 += ((c) >= E9) ? e_ : 0.f;  C9 += ((c) >= E9); } while (0)
                ACC(v.x); ACC(v.y); ACC(v.z); ACC(v.w);
#undef ACC
            }
        }
        // target element's g uses -x: swap its count from bin_of(xt) to bin_of(-xt).
        if (lane == 0) {
            const float nxt = -xt;
            C1 += (unsigned)(nxt >= E1) - (unsigned)(xt >= E1);  // modular, exact at the end
            C2 += (unsigned)(nxt >= E2) - (unsigned)(xt >= E2);
            C3 += (unsigned)(nxt >= E3) - (unsigned)(xt >= E3);
            C4 += (unsigned)(nxt >= E4) - (unsigned)(xt >= E4);
            C5 += (unsigned)(nxt >= E5) - (unsigned)(xt >= E5);
            C6 += (unsigned)(nxt >= E6) - (unsigned)(xt >= E6);
            C7 += (unsigned)(nxt >= E7) - (unsigned)(xt >= E7);
            C8 += (unsigned)(nxt >= E8) - (unsigned)(xt >= E8);
            C9 += (unsigned)(nxt >= E9) - (unsigned)(xt >= E9);
        }
        BFLY_F(T0); BFLY_F(T1); BFLY_F(T2); BFLY_F(T3); BFLY_F(T4);
        BFLY_F(T5); BFLY_F(T6); BFLY_F(T7); BFLY_F(T8); BFLY_F(T9);
        if (lane == 0) {
            float4* dst = reinterpret_cast<float4*>(Trows + (size_t)row * 12);
            dst[0] = make_float4(T0, T1, T2, T3);
            dst[1] = make_float4(T4, T5, T6, T7);
            dst[2] = make_float4(T8, T9, xt, 0.f);
        }
    }

    BFLY_U(C1); BFLY_U(C2); BFLY_U(C3); BFLY_U(C4); BFLY_U(C5);
    BFLY_U(C6); BFLY_U(C7); BFLY_U(C8); BFLY_U(C9);
    if (lane == 0) {
        cw[wid][0]=C1; cw[wid][1]=C2; cw[wid][2]=C3; cw[wid][3]=C4;
        cw[wid][4]=C5; cw[wid][5]=C6; cw[wid][6]=C7; cw[wid][7]=C8; cw[wid][8]=C9;
    }
    __syncthreads();
    if (tid < 9)   // bin-major for coalesced K2 reads
        partialC[tid * K1_BLKS + bid] = cw[0][tid] + cw[1][tid] + cw[2][tid] + cw[3][tid];
}

// K2: counts -> 10x10 weight table (LDS), one thread per row does
// denom = W[0]T0 + sum_b (W[b]-W[b-1])T_b + e^{xt}(1-W[bin(xt)]),
// loss = log(denom) - xt. Block partials; last block (ticket) folds the mean.
extern "C" __global__ __launch_bounds__(256)
void ghm_pass2(const unsigned int* __restrict__ partialC, const float* __restrict__ Trows,
               float* __restrict__ blockloss, unsigned int* __restrict__ ticket,
               float* __restrict__ out) {
    __shared__ float Cl[11];
    __shared__ float cnt[NBINS];
    __shared__ float Wt[NBINS][NBINS];
    __shared__ float red[4];
    __shared__ int   lastFlag;
    const int tid = threadIdx.x, wid = tid >> 6, lane = tid & 63;
    const int bid = blockIdx.x;

    // reduce partial cumulative counts (every block, coalesced, L2-resident)
    for (int b = wid; b < 9; b += 4) {
        unsigned int s = 0;
        for (int k = lane; k < K1_BLKS; k += 64) s += partialC[b * K1_BLKS + k];
        BFLY_U(s);
        if (lane == 0) Cl[b + 1] = (float)s;
    }
    if (tid == 0) { Cl[0] = C0_TOTAL; Cl[10] = 0.0f; }
    __syncthreads();
    if (tid < NBINS) cnt[tid] = Cl[tid] - Cl[tid + 1];   // all counts < 2^24: exact
    __syncthreads();
    if (tid < NBINS * NBINS) {
        const int tau = tid / NBINS, b = tid % NBINS;
        Wt[tau][b] = fminf(cnt[b] / cnt[tau], 1.0f);     // cnt[tau] >= 1 always
    }
    __syncthreads();

    const int row = bid * 256 + tid;                     // 128*256 = 32768 exactly
    const float4* Tp = reinterpret_cast<const float4*>(Trows + (size_t)row * 12);
    const float4 t0 = Tp[0];
    const float4 t1 = Tp[1];
    const float4 t2 = Tp[2];
    const float xt  = t2.z;
    const int   bt  = bin_of(-xt);                       // target g-bin
    const int   bxt = bin_of(xt);                        // target's natural x-bin
    const float* W  = Wt[bt];
    float d = W[0] * t0.x;
    d += (W[1] - W[0]) * t0.y;
    d += (W[2] - W[1]) * t0.z;
    d += (W[3] - W[2]) * t0.w;
    d += (W[4] - W[3]) * t1.x;
    d += (W[5] - W[4]) * t1.y;
    d += (W[6] - W[5]) * t1.z;
    d += (W[7] - W[6]) * t1.w;
    d += (W[8] - W[7]) * t2.x;
    d += (W[9] - W[8]) * t2.y;
    d += __expf(xt) * (1.0f - W[bxt]);                   // target weight is exactly 1
    float loss = __logf(d) - xt;

    BFLY_F(loss);
    if (lane == 0) red[wid] = loss;
    __syncthreads();
    if (tid == 0) {
        blockloss[bid] = (red[0] + red[1]) + (red[2] + red[3]);
        __threadfence();
        lastFlag = (atomicAdd(ticket, 1u) == K2_BLKS - 1);
    }
    __syncthreads();
    if (lastFlag) {                                      // block-uniform
        __threadfence();
        float s = 0.0f;
        if (tid < K2_BLKS)
            s = __hip_atomic_load(&blockloss[tid], __ATOMIC_RELAXED, __HIP_MEMORY_SCOPE_AGENT);
        BFLY_F(s);
        if (lane == 0) red[wid] = s;
        __syncthreads();
        if (tid == 0)
            out[0] = ((red[0] + red[1]) + (red[2] + red[3])) / (float)N_ROWS;
    }
}

extern "C" void kernel_launch(void* const* d_in, const int* in_sizes, int n_in,
                              void* d_out, int out_size, void* d_ws, size_t ws_size,
                              hipStream_t stream) {
    const float* x      = (const float*)d_in[0];
    const int*   target = (const int*)d_in[1];
    // ws layout (all regions fully overwritten before read each call):
    //   partialC @ 0       : 9*2048*4  = 73728 B
    //   ticket   @ 81920   : 4 B       (zeroed by K1 block 0)
    //   blockloss@ 82048   : 128*4 B
    //   Trows    @ 98304   : 32768*12*4 = 1572864 B
    unsigned int* partialC  = (unsigned int*)d_ws;
    unsigned int* ticket    = (unsigned int*)((char*)d_ws + 81920);
    float*        blockloss = (float*)((char*)d_ws + 82048);
    float*        Trows     = (float*)((char*)d_ws + 98304);

    hipLaunchKernelGGL(ghm_pass1, dim3(K1_BLKS), dim3(256), 0, stream,
                       x, target, partialC, Trows, ticket);
    hipLaunchKernelGGL(ghm_pass2, dim3(K2_BLKS), dim3(256), 0, stream,
                       partialC, Trows, blockloss, ticket, (float*)d_out);
}